// Round 1
// baseline (3919.050 us; speedup 1.0000x reference)
//
#include <hip/hip_runtime.h>

#define NN 100000
#define NE 400000
#define FD 128

// ---------------- degree / norm ----------------
__global__ void k_deg_init(float* __restrict__ norm) {
    int i = blockIdx.x * 256 + threadIdx.x;
    if (i < NN) norm[i] = 1.0f;   // self loop
}
__global__ void k_deg_count(const int* __restrict__ dst, float* __restrict__ norm) {
    int e = blockIdx.x * 256 + threadIdx.x;
    if (e < NE) unsafeAtomicAdd(&norm[dst[e]], 1.0f);
}
__global__ void k_norm_fin(float* __restrict__ norm) {
    int i = blockIdx.x * 256 + threadIdx.x;
    if (i < NN) norm[i] = rsqrtf(norm[i]);
}

// ---------------- propagation ----------------
// out[i] = in[i] * norm[row]  (works in-place too)
__global__ void k_scale_rows(const float4* __restrict__ in, float4* __restrict__ out,
                             const float* __restrict__ norm, int n4) {
    int i = blockIdx.x * 256 + threadIdx.x;
    if (i >= n4) return;
    int v = i >> 5;             // (i*4) / 128
    float s = norm[v];
    float4 a = in[i];
    a.x *= s; a.y *= s; a.z *= s; a.w *= s;
    out[i] = a;
}

// acc[dst[e]] += h_in[src[e]] * norm[src[e]]   (32 threads per edge, float4 loads)
__global__ void k_prop_edges(const float* __restrict__ h_in, float* __restrict__ h_out,
                             const float* __restrict__ norm,
                             const int* __restrict__ src, const int* __restrict__ dst) {
    int t = blockIdx.x * 256 + threadIdx.x;
    int e = t >> 5;
    if (e >= NE) return;
    int lane = t & 31;
    int s = src[e], d = dst[e];
    float ns = norm[s];
    const float4* hi = (const float4*)(h_in + (size_t)s * FD);
    float4 v = hi[lane];
    float* ho = h_out + (size_t)d * FD + lane * 4;
    unsafeAtomicAdd(ho + 0, v.x * ns);
    unsafeAtomicAdd(ho + 1, v.y * ns);
    unsafeAtomicAdd(ho + 2, v.z * ns);
    unsafeAtomicAdd(ho + 3, v.w * ns);
}

// ---------------- SGConv final linear: out = h @ W + b ----------------
__global__ __launch_bounds__(256) void k_sgconv(const float* __restrict__ h,
                                                const float* __restrict__ W,
                                                const float* __restrict__ b,
                                                float* __restrict__ out) {
    __shared__ float wl[FD * FD];     // 64 KB
    __shared__ float ht[16 * 132];    // 16 rows, padded
    int tid = threadIdx.x;
    int row0 = blockIdx.x * 16;
    for (int i = tid; i < FD * FD; i += 256) wl[i] = W[i];
    for (int i = tid; i < 16 * FD; i += 256) {
        int r = i >> 7, k = i & 127;
        ht[r * 132 + k] = h[(size_t)(row0 + r) * FD + k];
    }
    __syncthreads();
    int j = tid & 127, half = tid >> 7;
    float acc[8];
    float bj = b[j];
#pragma unroll
    for (int i = 0; i < 8; i++) acc[i] = bj;
    for (int k = 0; k < FD; k += 4) {
        float w0 = wl[(k + 0) * FD + j];
        float w1 = wl[(k + 1) * FD + j];
        float w2 = wl[(k + 2) * FD + j];
        float w3 = wl[(k + 3) * FD + j];
#pragma unroll
        for (int i = 0; i < 8; i++) {
            const float4 hv = *(const float4*)&ht[(half * 8 + i) * 132 + k];
            acc[i] += hv.x * w0 + hv.y * w1 + hv.z * w2 + hv.w * w3;
        }
    }
#pragma unroll
    for (int i = 0; i < 8; i++)
        out[(size_t)(row0 + half * 8 + i) * FD + j] = acc[i];
}

// ---------------- predict MLP (fused, pos+neg) ----------------
// block = 512 threads, 32 edges per block. grid = 25000 (12500 pos + 12500 neg)
__global__ __launch_bounds__(512) void k_predict(const float* __restrict__ h,
        const int* __restrict__ srcA, const int* __restrict__ dstA,
        const int* __restrict__ srcB, const int* __restrict__ dstB,
        const float* __restrict__ W1, const float* __restrict__ b1,
        const float* __restrict__ W2, const float* __restrict__ b2,
        const float* __restrict__ W3, const float* __restrict__ b3,
        float* __restrict__ out) {
    __shared__ float wl[FD * FD];     // 64 KB, W1 then W2
    __shared__ float za[32 * 132];    // 16.9 KB
    __shared__ float zb[32 * 132];
    int tid = threadIdx.x;
    int blk = blockIdx.x;
    int halfsel = blk >= 12500;
    int eb = (halfsel ? blk - 12500 : blk) * 32;
    const int* S = halfsel ? srcB : srcA;
    const int* D = halfsel ? dstB : dstA;
    int outoff = halfsel ? NE + eb : eb;

    // stage z = h[s] * h[d]  (16 threads per edge)
    {
        int e = tid >> 4, k0 = (tid & 15) * 8;
        int s = S[eb + e], d = D[eb + e];
        const float4* hs = (const float4*)(h + (size_t)s * FD + k0);
        const float4* hd = (const float4*)(h + (size_t)d * FD + k0);
        float4 a0 = hs[0], a1 = hs[1], c0 = hd[0], c1 = hd[1];
        float4 r0 = make_float4(a0.x * c0.x, a0.y * c0.y, a0.z * c0.z, a0.w * c0.w);
        float4 r1 = make_float4(a1.x * c1.x, a1.y * c1.y, a1.z * c1.z, a1.w * c1.w);
        *(float4*)&za[e * 132 + k0] = r0;
        *(float4*)&za[e * 132 + k0 + 4] = r1;
    }
    for (int i = tid; i < FD * FD; i += 512) wl[i] = W1[i];
    __syncthreads();

    int jp = tid & 63, eg = tid >> 6;
    int j0 = jp * 2, e0 = eg * 4;
    float acc[4][2];

    // ---- layer 1: za -> zb ----
    {
        float bb0 = b1[j0], bb1 = b1[j0 + 1];
#pragma unroll
        for (int i = 0; i < 4; i++) { acc[i][0] = bb0; acc[i][1] = bb1; }
        for (int k = 0; k < FD; k += 4) {
            float2 w0 = *(const float2*)&wl[(k + 0) * FD + j0];
            float2 w1 = *(const float2*)&wl[(k + 1) * FD + j0];
            float2 w2 = *(const float2*)&wl[(k + 2) * FD + j0];
            float2 w3 = *(const float2*)&wl[(k + 3) * FD + j0];
#pragma unroll
            for (int i = 0; i < 4; i++) {
                float4 zv = *(const float4*)&za[(e0 + i) * 132 + k];
                acc[i][0] += zv.x * w0.x + zv.y * w1.x + zv.z * w2.x + zv.w * w3.x;
                acc[i][1] += zv.x * w0.y + zv.y * w1.y + zv.z * w2.y + zv.w * w3.y;
            }
        }
        __syncthreads();   // all W1/za reads done
#pragma unroll
        for (int i = 0; i < 4; i++) {
            float2 r;
            r.x = fmaxf(acc[i][0], 0.0f);
            r.y = fmaxf(acc[i][1], 0.0f);
            *(float2*)&zb[(e0 + i) * 132 + j0] = r;
        }
        for (int i = tid; i < FD * FD; i += 512) wl[i] = W2[i];
        __syncthreads();   // W2 + zb ready
    }

    // ---- layer 2: zb -> za ----
    {
        float bb0 = b2[j0], bb1 = b2[j0 + 1];
#pragma unroll
        for (int i = 0; i < 4; i++) { acc[i][0] = bb0; acc[i][1] = bb1; }
        for (int k = 0; k < FD; k += 4) {
            float2 w0 = *(const float2*)&wl[(k + 0) * FD + j0];
            float2 w1 = *(const float2*)&wl[(k + 1) * FD + j0];
            float2 w2 = *(const float2*)&wl[(k + 2) * FD + j0];
            float2 w3 = *(const float2*)&wl[(k + 3) * FD + j0];
#pragma unroll
            for (int i = 0; i < 4; i++) {
                float4 zv = *(const float4*)&zb[(e0 + i) * 132 + k];
                acc[i][0] += zv.x * w0.x + zv.y * w1.x + zv.z * w2.x + zv.w * w3.x;
                acc[i][1] += zv.x * w0.y + zv.y * w1.y + zv.z * w2.y + zv.w * w3.y;
            }
        }
        __syncthreads();   // all zb/W2 reads done (za reads finished long ago)
#pragma unroll
        for (int i = 0; i < 4; i++) {
            float2 r;
            r.x = fmaxf(acc[i][0], 0.0f);
            r.y = fmaxf(acc[i][1], 0.0f);
            *(float2*)&za[(e0 + i) * 132 + j0] = r;
        }
        __syncthreads();
    }

    // ---- final layer: za @ W3 + b3 -> out ----
    {
        int wave = tid >> 6, lane = tid & 63;
        float w3a = W3[lane], w3b = W3[lane + 64];
        float bb3 = b3[0];
#pragma unroll
        for (int q = 0; q < 4; q++) {
            int e = wave * 4 + q;
            float v = za[e * 132 + lane] * w3a + za[e * 132 + lane + 64] * w3b;
            for (int off = 32; off; off >>= 1) v += __shfl_xor(v, off, 64);
            if (lane == 0) out[outoff + e] = v + bb3;
        }
    }
}

// ---------------- launch ----------------
extern "C" void kernel_launch(void* const* d_in, const int* in_sizes, int n_in,
                              void* d_out, int out_size, void* d_ws, size_t ws_size,
                              hipStream_t stream) {
    const float* x    = (const float*)d_in[0];
    const int* src    = (const int*)d_in[1];
    const int* dst    = (const int*)d_in[2];
    const int* nsrc   = (const int*)d_in[3];
    const int* ndst   = (const int*)d_in[4];
    const float* W_sg = (const float*)d_in[5];
    const float* b_sg = (const float*)d_in[6];
    const float* W1   = (const float*)d_in[7];
    const float* b1   = (const float*)d_in[8];
    const float* W2   = (const float*)d_in[9];
    const float* b2   = (const float*)d_in[10];
    const float* W3   = (const float*)d_in[11];
    const float* b3   = (const float*)d_in[12];
    float* out = (float*)d_out;

    float* norm = (float*)d_ws;                 // NN floats (400 KB, 16B-aligned tail)
    float* bufA = norm + NN;                    // NN*FD floats
    float* bufB = bufA + (size_t)NN * FD;

    const int n4 = NN * FD / 4;                 // 3.2M float4s
    const int gN = (NN + 255) / 256;
    const int gE = (NE + 255) / 256;
    const int g4 = (n4 + 255) / 256;

    k_deg_init<<<gN, 256, 0, stream>>>(norm);
    k_deg_count<<<gE, 256, 0, stream>>>(dst, norm);
    k_norm_fin<<<gN, 256, 0, stream>>>(norm);

    // hop 0: x -> bufA
    k_scale_rows<<<g4, 256, 0, stream>>>((const float4*)x, (float4*)bufA, norm, n4);
    k_prop_edges<<<NE * 32 / 256, 256, 0, stream>>>(x, bufA, norm, src, dst);
    k_scale_rows<<<g4, 256, 0, stream>>>((const float4*)bufA, (float4*)bufA, norm, n4);
    // hop 1: bufA -> bufB
    k_scale_rows<<<g4, 256, 0, stream>>>((const float4*)bufA, (float4*)bufB, norm, n4);
    k_prop_edges<<<NE * 32 / 256, 256, 0, stream>>>(bufA, bufB, norm, src, dst);
    k_scale_rows<<<g4, 256, 0, stream>>>((const float4*)bufB, (float4*)bufB, norm, n4);
    // hop 2: bufB -> bufA
    k_scale_rows<<<g4, 256, 0, stream>>>((const float4*)bufB, (float4*)bufA, norm, n4);
    k_prop_edges<<<NE * 32 / 256, 256, 0, stream>>>(bufB, bufA, norm, src, dst);
    k_scale_rows<<<g4, 256, 0, stream>>>((const float4*)bufA, (float4*)bufA, norm, n4);

    // SGConv linear: bufA @ W_sg + b_sg -> bufB
    k_sgconv<<<NN / 16, 256, 0, stream>>>(bufA, W_sg, b_sg, bufB);

    // predict (pos + neg)
    k_predict<<<25000, 512, 0, stream>>>(bufB, src, dst, nsrc, ndst,
                                         W1, b1, W2, b2, W3, b3, out);
}

// Round 2
// 2406.847 us; speedup vs baseline: 1.6283x; 1.6283x over previous
//
#include <hip/hip_runtime.h>

#define NN 100000
#define NE 400000
#define FD 128

typedef __attribute__((ext_vector_type(8))) short bf16x8;
typedef __attribute__((ext_vector_type(4))) float f32x4;

__device__ inline unsigned short f2bf(float f) {
    unsigned u = __float_as_uint(f);
    unsigned r = u + 0x7fff + ((u >> 16) & 1);
    return (unsigned short)(r >> 16);
}
__device__ inline float bf2f(unsigned short h) {
    return __uint_as_float(((unsigned)h) << 16);
}
// elementwise product of two bf16x2 words, result rounded to bf16x2
__device__ inline unsigned mulbf2(unsigned a, unsigned c) {
    float a0 = __uint_as_float(a << 16), a1 = __uint_as_float(a & 0xffff0000u);
    float c0 = __uint_as_float(c << 16), c1 = __uint_as_float(c & 0xffff0000u);
    unsigned r0 = f2bf(a0 * c0);
    unsigned r1 = f2bf(a1 * c1);
    return r0 | (r1 << 16);
}

// ---------------- degree / norm ----------------
__global__ void k_deg_init(float* __restrict__ norm) {
    int i = blockIdx.x * 256 + threadIdx.x;
    if (i < NN) norm[i] = 1.0f;
}
__global__ void k_deg_count(const int* __restrict__ dst, float* __restrict__ norm) {
    int e = blockIdx.x * 256 + threadIdx.x;
    if (e < NE) unsafeAtomicAdd(&norm[dst[e]], 1.0f);
}
__global__ void k_norm_fin(float* __restrict__ norm) {
    int i = blockIdx.x * 256 + threadIdx.x;
    if (i < NN) norm[i] = rsqrtf(norm[i]);
}

// ---------------- propagation (unchanged from R1) ----------------
__global__ void k_scale_rows(const float4* __restrict__ in, float4* __restrict__ out,
                             const float* __restrict__ norm, int n4) {
    int i = blockIdx.x * 256 + threadIdx.x;
    if (i >= n4) return;
    int v = i >> 5;
    float s = norm[v];
    float4 a = in[i];
    a.x *= s; a.y *= s; a.z *= s; a.w *= s;
    out[i] = a;
}

__global__ void k_prop_edges(const float* __restrict__ h_in, float* __restrict__ h_out,
                             const float* __restrict__ norm,
                             const int* __restrict__ src, const int* __restrict__ dst) {
    int t = blockIdx.x * 256 + threadIdx.x;
    int e = t >> 5;
    if (e >= NE) return;
    int lane = t & 31;
    int s = src[e], d = dst[e];
    float ns = norm[s];
    const float4* hi = (const float4*)(h_in + (size_t)s * FD);
    float4 v = hi[lane];
    float* ho = h_out + (size_t)d * FD + lane * 4;
    unsafeAtomicAdd(ho + 0, v.x * ns);
    unsafeAtomicAdd(ho + 1, v.y * ns);
    unsafeAtomicAdd(ho + 2, v.z * ns);
    unsafeAtomicAdd(ho + 3, v.w * ns);
}

// ---------------- weight packing: f32 [128][128] -> bf16 MFMA fragments ----
// frag (nt, kb), lane l, elem j  =  W[32*kb + 8*(l>>4) + j][16*nt + (l&15)]
// stored at wp[frag*64 + l] as uint4 (8 bf16, j ascending)
__global__ void k_pack_w(const float* __restrict__ Wsg, const float* __restrict__ W1,
                         const float* __restrict__ W2, uint4* __restrict__ wp) {
    int t = blockIdx.x * 256 + threadIdx.x;   // 0..6143
    int wsel = t >> 11, r = t & 2047;
    const float* W = wsel == 0 ? Wsg : (wsel == 1 ? W1 : W2);
    int frag = r >> 6, l = r & 63;
    int nt = frag >> 2, kb = frag & 3;
    int col = 16 * nt + (l & 15);
    int k0 = 32 * kb + 8 * (l >> 4);
    unsigned q[4];
#pragma unroll
    for (int j = 0; j < 4; j++) {
        unsigned lo = f2bf(W[(size_t)(k0 + 2 * j) * FD + col]);
        unsigned hi = f2bf(W[(size_t)(k0 + 2 * j + 1) * FD + col]);
        q[j] = lo | (hi << 16);
    }
    wp[t] = make_uint4(q[0], q[1], q[2], q[3]);
}

#define ZS 136   // z row stride in bf16 (272 B: 16B-aligned, bank-spread)

// ---------------- SGConv linear via MFMA: hout(bf16) = hin @ Wsg + bsg ------
__global__ __launch_bounds__(128) void k_sgconv_mfma(const float* __restrict__ hin,
        const uint4* __restrict__ wp, const float* __restrict__ bsg,
        unsigned short* __restrict__ hout) {
    __shared__ unsigned short z[128 * ZS];
    __shared__ uint4 wl[2048];
    int tid = threadIdx.x;
    int row0 = blockIdx.x * 128;
    for (int i = tid; i < 2048; i += 128) wl[i] = wp[i];
    // stage 128 rows f32 -> bf16
#pragma unroll 4
    for (int it = 0; it < 32; it++) {
        int idx = it * 128 + tid;          // float4 id, 32 per row
        int r = idx >> 5, c4 = idx & 31;
        float4 v = make_float4(0, 0, 0, 0);
        if (row0 + r < NN) v = *(const float4*)(hin + (size_t)(row0 + r) * FD + c4 * 4);
        unsigned lo = f2bf(v.x) | ((unsigned)f2bf(v.y) << 16);
        unsigned hi = f2bf(v.z) | ((unsigned)f2bf(v.w) << 16);
        *(uint2*)&z[r * ZS + c4 * 4] = make_uint2(lo, hi);
    }
    __syncthreads();

    int l = tid & 63, w = tid >> 6;
    f32x4 acc[4][8];
#pragma unroll
    for (int mt = 0; mt < 4; mt++)
#pragma unroll
        for (int nt = 0; nt < 8; nt++) acc[mt][nt] = (f32x4){0, 0, 0, 0};

#pragma unroll
    for (int kb = 0; kb < 4; kb++) {
        bf16x8 af[4];
#pragma unroll
        for (int mt = 0; mt < 4; mt++)
            af[mt] = *(const bf16x8*)&z[(w * 64 + mt * 16 + (l & 15)) * ZS + kb * 32 + (l >> 4) * 8];
#pragma unroll
        for (int nt = 0; nt < 8; nt++) {
            bf16x8 wf = *(const bf16x8*)((const unsigned short*)wl + ((nt * 4 + kb) * 64 + l) * 8);
#pragma unroll
            for (int mt = 0; mt < 4; mt++)
                acc[mt][nt] = __builtin_amdgcn_mfma_f32_16x16x32_bf16(af[mt], wf, acc[mt][nt], 0, 0, 0);
        }
    }
    __syncthreads();
    // write back (+bias) to z as bf16, then vector-store
    float bv[8];
#pragma unroll
    for (int nt = 0; nt < 8; nt++) bv[nt] = bsg[16 * nt + (l & 15)];
#pragma unroll
    for (int mt = 0; mt < 4; mt++)
#pragma unroll
        for (int nt = 0; nt < 8; nt++)
#pragma unroll
            for (int r = 0; r < 4; r++)
                z[(w * 64 + mt * 16 + (l >> 4) * 4 + r) * ZS + 16 * nt + (l & 15)] =
                    f2bf(acc[mt][nt][r] + bv[nt]);
    __syncthreads();
#pragma unroll 4
    for (int it = 0; it < 16; it++) {
        int idx = it * 128 + tid;          // uint4 id, 16 per row
        int r = idx >> 4, c = idx & 15;
        if (row0 + r < NN)
            *(uint4*)(hout + (size_t)(row0 + r) * FD + c * 8) = *(const uint4*)&z[r * ZS + c * 8];
    }
}

// ---------------- predict MLP via MFMA (pos+neg) ----------------
// 128 edges / block, 2 waves; wave covers 64 edge-rows (4 m-tiles)
__global__ __launch_bounds__(128) void k_predict_mfma(const unsigned short* __restrict__ h,
        const int* __restrict__ srcA, const int* __restrict__ dstA,
        const int* __restrict__ srcB, const int* __restrict__ dstB,
        const uint4* __restrict__ w1p, const uint4* __restrict__ w2p,
        const float* __restrict__ b1, const float* __restrict__ b2,
        const float* __restrict__ W3, const float* __restrict__ b3,
        float* __restrict__ out) {
    __shared__ unsigned short z[128 * ZS];
    __shared__ uint4 wl[2048];
    int tid = threadIdx.x;
    int b = blockIdx.x;
    int half = b >= 3125;
    int eb = (b - (half ? 3125 : 0)) * 128;
    const int* S = half ? srcB : srcA;
    const int* D = half ? dstB : dstA;

    for (int i = tid; i < 2048; i += 128) wl[i] = w1p[i];
    // stage z = h[s] * h[d]  (bf16); 4 threads per edge (64B each of hs,hd)
#pragma unroll
    for (int it = 0; it < 4; it++) {
        int e = (tid >> 2) + 32 * it;
        int p = tid & 3;
        int s = S[eb + e], d = D[eb + e];
        const uint4* hs = (const uint4*)(h + (size_t)s * FD + p * 32);
        const uint4* hd = (const uint4*)(h + (size_t)d * FD + p * 32);
        unsigned short* zr = z + e * ZS + p * 32;
#pragma unroll
        for (int q = 0; q < 4; q++) {
            uint4 a = hs[q], c = hd[q];
            uint4 r;
            r.x = mulbf2(a.x, c.x);
            r.y = mulbf2(a.y, c.y);
            r.z = mulbf2(a.z, c.z);
            r.w = mulbf2(a.w, c.w);
            *(uint4*)(zr + q * 8) = r;
        }
    }
    __syncthreads();

    int l = tid & 63, w = tid >> 6;
    f32x4 acc[4][8];
#pragma unroll
    for (int mt = 0; mt < 4; mt++)
#pragma unroll
        for (int nt = 0; nt < 8; nt++) acc[mt][nt] = (f32x4){0, 0, 0, 0};

    // ---- layer 1 ----
#pragma unroll
    for (int kb = 0; kb < 4; kb++) {
        bf16x8 af[4];
#pragma unroll
        for (int mt = 0; mt < 4; mt++)
            af[mt] = *(const bf16x8*)&z[(w * 64 + mt * 16 + (l & 15)) * ZS + kb * 32 + (l >> 4) * 8];
#pragma unroll
        for (int nt = 0; nt < 8; nt++) {
            bf16x8 wf = *(const bf16x8*)((const unsigned short*)wl + ((nt * 4 + kb) * 64 + l) * 8);
#pragma unroll
            for (int mt = 0; mt < 4; mt++)
                acc[mt][nt] = __builtin_amdgcn_mfma_f32_16x16x32_bf16(af[mt], wf, acc[mt][nt], 0, 0, 0);
        }
    }
    __syncthreads();          // all W1 reads done
    // stage W2, write relu(acc + b1) back to z (own rows only)
    for (int i = tid; i < 2048; i += 128) wl[i] = w2p[i];
    {
        float bv[8];
#pragma unroll
        for (int nt = 0; nt < 8; nt++) bv[nt] = b1[16 * nt + (l & 15)];
#pragma unroll
        for (int mt = 0; mt < 4; mt++)
#pragma unroll
            for (int nt = 0; nt < 8; nt++)
#pragma unroll
                for (int r = 0; r < 4; r++)
                    z[(w * 64 + mt * 16 + (l >> 4) * 4 + r) * ZS + 16 * nt + (l & 15)] =
                        f2bf(fmaxf(acc[mt][nt][r] + bv[nt], 0.0f));
    }
    __syncthreads();

    // ---- layer 2 ----
#pragma unroll
    for (int mt = 0; mt < 4; mt++)
#pragma unroll
        for (int nt = 0; nt < 8; nt++) acc[mt][nt] = (f32x4){0, 0, 0, 0};
#pragma unroll
    for (int kb = 0; kb < 4; kb++) {
        bf16x8 af[4];
#pragma unroll
        for (int mt = 0; mt < 4; mt++)
            af[mt] = *(const bf16x8*)&z[(w * 64 + mt * 16 + (l & 15)) * ZS + kb * 32 + (l >> 4) * 8];
#pragma unroll
        for (int nt = 0; nt < 8; nt++) {
            bf16x8 wf = *(const bf16x8*)((const unsigned short*)wl + ((nt * 4 + kb) * 64 + l) * 8);
#pragma unroll
            for (int mt = 0; mt < 4; mt++)
                acc[mt][nt] = __builtin_amdgcn_mfma_f32_16x16x32_bf16(af[mt], wf, acc[mt][nt], 0, 0, 0);
        }
    }

    // ---- epilogue: relu(acc + b2) . W3 + b3 ----
    {
        float w3v[8], bv[8];
#pragma unroll
        for (int nt = 0; nt < 8; nt++) {
            w3v[nt] = W3[16 * nt + (l & 15)];
            bv[nt] = b2[16 * nt + (l & 15)];
        }
        float bb3 = b3[0];
#pragma unroll
        for (int mt = 0; mt < 4; mt++)
#pragma unroll
            for (int r = 0; r < 4; r++) {
                float p = 0.0f;
#pragma unroll
                for (int nt = 0; nt < 8; nt++)
                    p += fmaxf(acc[mt][nt][r] + bv[nt], 0.0f) * w3v[nt];
                p += __shfl_xor(p, 1);
                p += __shfl_xor(p, 2);
                p += __shfl_xor(p, 4);
                p += __shfl_xor(p, 8);
                if ((l & 15) == 0)
                    out[(size_t)half * NE + eb + w * 64 + mt * 16 + (l >> 4) * 4 + r] = p + bb3;
            }
    }
}

// ---------------- launch ----------------
extern "C" void kernel_launch(void* const* d_in, const int* in_sizes, int n_in,
                              void* d_out, int out_size, void* d_ws, size_t ws_size,
                              hipStream_t stream) {
    const float* x    = (const float*)d_in[0];
    const int* src    = (const int*)d_in[1];
    const int* dst    = (const int*)d_in[2];
    const int* nsrc   = (const int*)d_in[3];
    const int* ndst   = (const int*)d_in[4];
    const float* W_sg = (const float*)d_in[5];
    const float* b_sg = (const float*)d_in[6];
    const float* W1   = (const float*)d_in[7];
    const float* b1   = (const float*)d_in[8];
    const float* W2   = (const float*)d_in[9];
    const float* b2   = (const float*)d_in[10];
    const float* W3   = (const float*)d_in[11];
    const float* b3   = (const float*)d_in[12];
    float* out = (float*)d_out;

    float* norm = (float*)d_ws;                                  // 400000 B
    uint4* wp   = (uint4*)((char*)d_ws + 400000);                // 3 x 32768 B
    float* bufA = (float*)((char*)d_ws + 400000 + 98304);
    float* bufB = bufA + (size_t)NN * FD;
    unsigned short* hbf = (unsigned short*)bufB;                 // reuse bufB after hops

    const int n4 = NN * FD / 4;
    const int gN = (NN + 255) / 256;
    const int gE = (NE + 255) / 256;
    const int g4 = (n4 + 255) / 256;

    k_pack_w<<<24, 256, 0, stream>>>(W_sg, W1, W2, wp);

    k_deg_init<<<gN, 256, 0, stream>>>(norm);
    k_deg_count<<<gE, 256, 0, stream>>>(dst, norm);
    k_norm_fin<<<gN, 256, 0, stream>>>(norm);

    // hop 0: x -> bufA
    k_scale_rows<<<g4, 256, 0, stream>>>((const float4*)x, (float4*)bufA, norm, n4);
    k_prop_edges<<<NE * 32 / 256, 256, 0, stream>>>(x, bufA, norm, src, dst);
    k_scale_rows<<<g4, 256, 0, stream>>>((const float4*)bufA, (float4*)bufA, norm, n4);
    // hop 1: bufA -> bufB
    k_scale_rows<<<g4, 256, 0, stream>>>((const float4*)bufA, (float4*)bufB, norm, n4);
    k_prop_edges<<<NE * 32 / 256, 256, 0, stream>>>(bufA, bufB, norm, src, dst);
    k_scale_rows<<<g4, 256, 0, stream>>>((const float4*)bufB, (float4*)bufB, norm, n4);
    // hop 2: bufB -> bufA
    k_scale_rows<<<g4, 256, 0, stream>>>((const float4*)bufB, (float4*)bufA, norm, n4);
    k_prop_edges<<<NE * 32 / 256, 256, 0, stream>>>(bufB, bufA, norm, src, dst);
    k_scale_rows<<<g4, 256, 0, stream>>>((const float4*)bufA, (float4*)bufA, norm, n4);

    // SGConv linear (MFMA) -> bf16 h
    k_sgconv_mfma<<<(NN + 127) / 128, 128, 0, stream>>>(bufA, wp, b_sg, hbf);

    // predict MLP (MFMA), pos + neg
    k_predict_mfma<<<6250, 128, 0, stream>>>(hbf, src, dst, nsrc, ndst,
                                             wp + 2048, wp + 4096,
                                             b1, b2, W3, b3, out);
}

// Round 3
// 537.475 us; speedup vs baseline: 7.2916x; 4.4781x over previous
//
#include <hip/hip_runtime.h>

#define NN 100000
#define NE 400000
#define FD 128
#define SCAN_B 1024

typedef __attribute__((ext_vector_type(8))) short bf16x8;
typedef __attribute__((ext_vector_type(4))) float f32x4;

__device__ inline unsigned short f2bf(float f) {
    unsigned u = __float_as_uint(f);
    unsigned r = u + 0x7fff + ((u >> 16) & 1);
    return (unsigned short)(r >> 16);
}
__device__ inline unsigned mulbf2(unsigned a, unsigned c) {
    float a0 = __uint_as_float(a << 16), a1 = __uint_as_float(a & 0xffff0000u);
    float c0 = __uint_as_float(c << 16), c1 = __uint_as_float(c & 0xffff0000u);
    unsigned r0 = f2bf(a0 * c0);
    unsigned r1 = f2bf(a1 * c1);
    return r0 | (r1 << 16);
}

// ---------------- degree / norm / CSR ----------------
__global__ void k_deg_init(int* __restrict__ deg) {
    int i = blockIdx.x * 256 + threadIdx.x;
    if (i < NN) deg[i] = 0;
}
__global__ void k_deg_count(const int* __restrict__ dst, int* __restrict__ deg) {
    int e = blockIdx.x * 256 + threadIdx.x;
    if (e < NE) atomicAdd(&deg[dst[e]], 1);
}
__global__ void k_norm(const int* __restrict__ deg, float* __restrict__ norm) {
    int i = blockIdx.x * 256 + threadIdx.x;
    if (i < NN) norm[i] = rsqrtf((float)(deg[i] + 1));
}
__global__ __launch_bounds__(SCAN_B) void k_scan1(const int* __restrict__ deg,
                                                  int* __restrict__ off,
                                                  int* __restrict__ bsum) {
    __shared__ int s[SCAN_B];
    int t = threadIdx.x, g = blockIdx.x * SCAN_B + t;
    s[t] = (g < NN) ? deg[g] : 0;
    __syncthreads();
    for (int d = 1; d < SCAN_B; d <<= 1) {
        int add = (t >= d) ? s[t - d] : 0;
        __syncthreads();
        s[t] += add;
        __syncthreads();
    }
    if (g < NN) off[g + 1] = s[t];
    if (t == SCAN_B - 1) bsum[blockIdx.x] = s[t];
}
__global__ void k_scan2(int* __restrict__ bsum, int nb) {
    if (threadIdx.x == 0 && blockIdx.x == 0) {
        int acc = 0;
        for (int i = 0; i < nb; i++) { int v = bsum[i]; bsum[i] = acc; acc += v; }
    }
}
__global__ void k_scan3(int* __restrict__ off, const int* __restrict__ bsum) {
    int g = blockIdx.x * 256 + threadIdx.x;
    if (g == 0) off[0] = 0;
    if (g < NN) off[g + 1] += bsum[g / SCAN_B];
}
__global__ void k_cur(const int* __restrict__ off, int* __restrict__ cur) {
    int g = blockIdx.x * 256 + threadIdx.x;
    if (g < NN) cur[g] = off[g];
}
__global__ void k_fill(const int* __restrict__ src, const int* __restrict__ dst,
                       int* __restrict__ cur, int* __restrict__ csr) {
    int e = blockIdx.x * 256 + threadIdx.x;
    if (e < NE) {
        int p = atomicAdd(&cur[dst[e]], 1);
        csr[p] = src[e];
    }
}

// ---------------- propagation: CSR gather, no atomics ----------------
__global__ __launch_bounds__(256) void k_prop_gather(const float* __restrict__ h_in,
        float* __restrict__ h_out, const float* __restrict__ norm,
        const int* __restrict__ off, const int* __restrict__ csr) {
    int t = blockIdx.x * 256 + threadIdx.x;
    int v = t >> 5, lane = t & 31;
    float nv = norm[v];
    float4 a = ((const float4*)(h_in + (size_t)v * FD))[lane];
    float4 acc = make_float4(a.x * nv, a.y * nv, a.z * nv, a.w * nv);
    int j1 = off[v + 1];
    for (int j = off[v]; j < j1; j++) {
        int s = csr[j];
        float ns = norm[s];
        float4 b = ((const float4*)(h_in + (size_t)s * FD))[lane];
        acc.x += ns * b.x; acc.y += ns * b.y; acc.z += ns * b.z; acc.w += ns * b.w;
    }
    acc.x *= nv; acc.y *= nv; acc.z *= nv; acc.w *= nv;
    ((float4*)(h_out + (size_t)v * FD))[lane] = acc;
}

// ---------------- weight packing ----------------
__global__ void k_pack_w(const float* __restrict__ Wsg, const float* __restrict__ W1,
                         const float* __restrict__ W2, uint4* __restrict__ wp) {
    int t = blockIdx.x * 256 + threadIdx.x;
    int wsel = t >> 11, r = t & 2047;
    const float* W = wsel == 0 ? Wsg : (wsel == 1 ? W1 : W2);
    int frag = r >> 6, l = r & 63;
    int nt = frag >> 2, kb = frag & 3;
    int col = 16 * nt + (l & 15);
    int k0 = 32 * kb + 8 * (l >> 4);
    unsigned q[4];
#pragma unroll
    for (int j = 0; j < 4; j++) {
        unsigned lo = f2bf(W[(size_t)(k0 + 2 * j) * FD + col]);
        unsigned hi = f2bf(W[(size_t)(k0 + 2 * j + 1) * FD + col]);
        q[j] = lo | (hi << 16);
    }
    wp[t] = make_uint4(q[0], q[1], q[2], q[3]);
}

#define ZS 136

// ---------------- SGConv linear via MFMA ----------------
__global__ __launch_bounds__(128) void k_sgconv_mfma(const float* __restrict__ hin,
        const uint4* __restrict__ wp, const float* __restrict__ bsg,
        unsigned short* __restrict__ hout) {
    __shared__ unsigned short z[128 * ZS];
    __shared__ uint4 wl[2048];
    int tid = threadIdx.x;
    int row0 = blockIdx.x * 128;
    for (int i = tid; i < 2048; i += 128) wl[i] = wp[i];
#pragma unroll 4
    for (int it = 0; it < 32; it++) {
        int idx = it * 128 + tid;
        int r = idx >> 5, c4 = idx & 31;
        float4 v = make_float4(0, 0, 0, 0);
        if (row0 + r < NN) v = *(const float4*)(hin + (size_t)(row0 + r) * FD + c4 * 4);
        unsigned lo = f2bf(v.x) | ((unsigned)f2bf(v.y) << 16);
        unsigned hi = f2bf(v.z) | ((unsigned)f2bf(v.w) << 16);
        *(uint2*)&z[r * ZS + c4 * 4] = make_uint2(lo, hi);
    }
    __syncthreads();

    int l = tid & 63, w = tid >> 6;
    f32x4 acc[4][8];
#pragma unroll
    for (int mt = 0; mt < 4; mt++)
#pragma unroll
        for (int nt = 0; nt < 8; nt++) acc[mt][nt] = (f32x4){0, 0, 0, 0};

#pragma unroll
    for (int kb = 0; kb < 4; kb++) {
        bf16x8 af[4];
#pragma unroll
        for (int mt = 0; mt < 4; mt++)
            af[mt] = *(const bf16x8*)&z[(w * 64 + mt * 16 + (l & 15)) * ZS + kb * 32 + (l >> 4) * 8];
#pragma unroll
        for (int nt = 0; nt < 8; nt++) {
            bf16x8 wf = *(const bf16x8*)((const unsigned short*)wl + ((nt * 4 + kb) * 64 + l) * 8);
#pragma unroll
            for (int mt = 0; mt < 4; mt++)
                acc[mt][nt] = __builtin_amdgcn_mfma_f32_16x16x32_bf16(af[mt], wf, acc[mt][nt], 0, 0, 0);
        }
    }
    __syncthreads();
    float bv[8];
#pragma unroll
    for (int nt = 0; nt < 8; nt++) bv[nt] = bsg[16 * nt + (l & 15)];
#pragma unroll
    for (int mt = 0; mt < 4; mt++)
#pragma unroll
        for (int nt = 0; nt < 8; nt++)
#pragma unroll
            for (int r = 0; r < 4; r++)
                z[(w * 64 + mt * 16 + (l >> 4) * 4 + r) * ZS + 16 * nt + (l & 15)] =
                    f2bf(acc[mt][nt][r] + bv[nt]);
    __syncthreads();
#pragma unroll 4
    for (int it = 0; it < 16; it++) {
        int idx = it * 128 + tid;
        int r = idx >> 4, c = idx & 15;
        if (row0 + r < NN)
            *(uint4*)(hout + (size_t)(row0 + r) * FD + c * 8) = *(const uint4*)&z[r * ZS + c * 8];
    }
}

// ---------------- predict MLP via MFMA (pos+neg) ----------------
__global__ __launch_bounds__(128) void k_predict_mfma(const unsigned short* __restrict__ h,
        const int* __restrict__ srcA, const int* __restrict__ dstA,
        const int* __restrict__ srcB, const int* __restrict__ dstB,
        const uint4* __restrict__ w1p, const uint4* __restrict__ w2p,
        const float* __restrict__ b1, const float* __restrict__ b2,
        const float* __restrict__ W3, const float* __restrict__ b3,
        float* __restrict__ out) {
    __shared__ unsigned short z[128 * ZS];
    __shared__ uint4 wl[2048];
    int tid = threadIdx.x;
    int b = blockIdx.x;
    int half = b >= 3125;
    int eb = (b - (half ? 3125 : 0)) * 128;
    const int* S = half ? srcB : srcA;
    const int* D = half ? dstB : dstA;

    for (int i = tid; i < 2048; i += 128) wl[i] = w1p[i];
#pragma unroll
    for (int it = 0; it < 4; it++) {
        int e = (tid >> 2) + 32 * it;
        int p = tid & 3;
        int s = S[eb + e], d = D[eb + e];
        const uint4* hs = (const uint4*)(h + (size_t)s * FD + p * 32);
        const uint4* hd = (const uint4*)(h + (size_t)d * FD + p * 32);
        unsigned short* zr = z + e * ZS + p * 32;
#pragma unroll
        for (int q = 0; q < 4; q++) {
            uint4 a = hs[q], c = hd[q];
            uint4 r;
            r.x = mulbf2(a.x, c.x);
            r.y = mulbf2(a.y, c.y);
            r.z = mulbf2(a.z, c.z);
            r.w = mulbf2(a.w, c.w);
            *(uint4*)(zr + q * 8) = r;
        }
    }
    __syncthreads();

    int l = tid & 63, w = tid >> 6;
    f32x4 acc[4][8];
#pragma unroll
    for (int mt = 0; mt < 4; mt++)
#pragma unroll
        for (int nt = 0; nt < 8; nt++) acc[mt][nt] = (f32x4){0, 0, 0, 0};

#pragma unroll
    for (int kb = 0; kb < 4; kb++) {
        bf16x8 af[4];
#pragma unroll
        for (int mt = 0; mt < 4; mt++)
            af[mt] = *(const bf16x8*)&z[(w * 64 + mt * 16 + (l & 15)) * ZS + kb * 32 + (l >> 4) * 8];
#pragma unroll
        for (int nt = 0; nt < 8; nt++) {
            bf16x8 wf = *(const bf16x8*)((const unsigned short*)wl + ((nt * 4 + kb) * 64 + l) * 8);
#pragma unroll
            for (int mt = 0; mt < 4; mt++)
                acc[mt][nt] = __builtin_amdgcn_mfma_f32_16x16x32_bf16(af[mt], wf, acc[mt][nt], 0, 0, 0);
        }
    }
    __syncthreads();
    for (int i = tid; i < 2048; i += 128) wl[i] = w2p[i];
    {
        float bv[8];
#pragma unroll
        for (int nt = 0; nt < 8; nt++) bv[nt] = b1[16 * nt + (l & 15)];
#pragma unroll
        for (int mt = 0; mt < 4; mt++)
#pragma unroll
            for (int nt = 0; nt < 8; nt++)
#pragma unroll
                for (int r = 0; r < 4; r++)
                    z[(w * 64 + mt * 16 + (l >> 4) * 4 + r) * ZS + 16 * nt + (l & 15)] =
                        f2bf(fmaxf(acc[mt][nt][r] + bv[nt], 0.0f));
    }
    __syncthreads();

#pragma unroll
    for (int mt = 0; mt < 4; mt++)
#pragma unroll
        for (int nt = 0; nt < 8; nt++) acc[mt][nt] = (f32x4){0, 0, 0, 0};
#pragma unroll
    for (int kb = 0; kb < 4; kb++) {
        bf16x8 af[4];
#pragma unroll
        for (int mt = 0; mt < 4; mt++)
            af[mt] = *(const bf16x8*)&z[(w * 64 + mt * 16 + (l & 15)) * ZS + kb * 32 + (l >> 4) * 8];
#pragma unroll
        for (int nt = 0; nt < 8; nt++) {
            bf16x8 wf = *(const bf16x8*)((const unsigned short*)wl + ((nt * 4 + kb) * 64 + l) * 8);
#pragma unroll
            for (int mt = 0; mt < 4; mt++)
                acc[mt][nt] = __builtin_amdgcn_mfma_f32_16x16x32_bf16(af[mt], wf, acc[mt][nt], 0, 0, 0);
        }
    }

    {
        float w3v[8], bv[8];
#pragma unroll
        for (int nt = 0; nt < 8; nt++) {
            w3v[nt] = W3[16 * nt + (l & 15)];
            bv[nt] = b2[16 * nt + (l & 15)];
        }
        float bb3 = b3[0];
#pragma unroll
        for (int mt = 0; mt < 4; mt++)
#pragma unroll
            for (int r = 0; r < 4; r++) {
                float p = 0.0f;
#pragma unroll
                for (int nt = 0; nt < 8; nt++)
                    p += fmaxf(acc[mt][nt][r] + bv[nt], 0.0f) * w3v[nt];
                p += __shfl_xor(p, 1);
                p += __shfl_xor(p, 2);
                p += __shfl_xor(p, 4);
                p += __shfl_xor(p, 8);
                if ((l & 15) == 0)
                    out[(size_t)half * NE + eb + w * 64 + mt * 16 + (l >> 4) * 4 + r] = p + bb3;
            }
    }
}

// ---------------- launch ----------------
extern "C" void kernel_launch(void* const* d_in, const int* in_sizes, int n_in,
                              void* d_out, int out_size, void* d_ws, size_t ws_size,
                              hipStream_t stream) {
    const float* x    = (const float*)d_in[0];
    const int* src    = (const int*)d_in[1];
    const int* dst    = (const int*)d_in[2];
    const int* nsrc   = (const int*)d_in[3];
    const int* ndst   = (const int*)d_in[4];
    const float* W_sg = (const float*)d_in[5];
    const float* b_sg = (const float*)d_in[6];
    const float* W1   = (const float*)d_in[7];
    const float* b1   = (const float*)d_in[8];
    const float* W2   = (const float*)d_in[9];
    const float* b2   = (const float*)d_in[10];
    const float* W3   = (const float*)d_in[11];
    const float* b3   = (const float*)d_in[12];
    float* out = (float*)d_out;

    char* p = (char*)d_ws;
    float* norm = (float*)p;  p += 400000;               // NN f32
    int*   deg  = (int*)p;    p += 400000;               // NN i32
    int*   off  = (int*)p;    p += 400016;               // NN+1 i32
    int*   cur  = (int*)p;    p += 400000;               // NN i32
    int*   bsum = (int*)p;    p += 512;                  // 98 i32
    int*   csr  = (int*)p;    p += 1600000;              // NE i32
    uint4* wp   = (uint4*)p;  p += 98304;                // 3 x 2048 uint4
    float* bufA = (float*)p;  p += (size_t)NN * FD * 4;  // 51.2 MB
    float* bufB = (float*)p;                             // 51.2 MB
    unsigned short* hbf = (unsigned short*)bufB;

    const int gN = (NN + 255) / 256;
    const int gE = (NE + 255) / 256;
    const int nb = (NN + SCAN_B - 1) / SCAN_B;

    k_pack_w<<<24, 256, 0, stream>>>(W_sg, W1, W2, wp);

    // CSR build
    k_deg_init<<<gN, 256, 0, stream>>>(deg);
    k_deg_count<<<gE, 256, 0, stream>>>(dst, deg);
    k_norm<<<gN, 256, 0, stream>>>(deg, norm);
    k_scan1<<<nb, SCAN_B, 0, stream>>>(deg, off, bsum);
    k_scan2<<<1, 64, 0, stream>>>(bsum, nb);
    k_scan3<<<gN, 256, 0, stream>>>(off, bsum);
    k_cur<<<gN, 256, 0, stream>>>(off, cur);
    k_fill<<<gE, 256, 0, stream>>>(src, dst, cur, csr);

    // propagation: x -> bufA -> bufB -> bufA (norm folded in)
    k_prop_gather<<<NN * 32 / 256, 256, 0, stream>>>(x, bufA, norm, off, csr);
    k_prop_gather<<<NN * 32 / 256, 256, 0, stream>>>(bufA, bufB, norm, off, csr);
    k_prop_gather<<<NN * 32 / 256, 256, 0, stream>>>(bufB, bufA, norm, off, csr);

    // SGConv linear (MFMA) -> bf16 h (into bufB)
    k_sgconv_mfma<<<(NN + 127) / 128, 128, 0, stream>>>(bufA, wp, b_sg, hbf);

    // predict MLP (MFMA), pos + neg
    k_predict_mfma<<<6250, 128, 0, stream>>>(hbf, src, dst, nsrc, ndst,
                                             wp + 2048, wp + 4096,
                                             b1, b2, W3, b3, out);
}

// Round 4
// 382.276 us; speedup vs baseline: 10.2519x; 1.4060x over previous
//
#include <hip/hip_runtime.h>

#define NN 100000
#define NE 400000
#define FD 128
#define SCAN_B 1024

typedef __attribute__((ext_vector_type(8))) short bf16x8;
typedef __attribute__((ext_vector_type(4))) float f32x4;

__device__ inline unsigned short f2bf(float f) {
    unsigned u = __float_as_uint(f);
    unsigned r = u + 0x7fff + ((u >> 16) & 1);
    return (unsigned short)(r >> 16);
}
__device__ inline unsigned mulbf2(unsigned a, unsigned c) {
    float a0 = __uint_as_float(a << 16), a1 = __uint_as_float(a & 0xffff0000u);
    float c0 = __uint_as_float(c << 16), c1 = __uint_as_float(c & 0xffff0000u);
    unsigned r0 = f2bf(a0 * c0);
    unsigned r1 = f2bf(a1 * c1);
    return r0 | (r1 << 16);
}

// ---------------- degree / norm / CSR ----------------
__global__ void k_deg_init(int* __restrict__ deg) {
    int i = blockIdx.x * 256 + threadIdx.x;
    if (i < NN) deg[i] = 0;
}
__global__ void k_deg_count(const int* __restrict__ dst, int* __restrict__ deg) {
    int e = blockIdx.x * 256 + threadIdx.x;
    if (e < NE) atomicAdd(&deg[dst[e]], 1);
}
__global__ void k_norm(const int* __restrict__ deg, float* __restrict__ norm) {
    int i = blockIdx.x * 256 + threadIdx.x;
    if (i < NN) norm[i] = rsqrtf((float)(deg[i] + 1));
}
__global__ __launch_bounds__(SCAN_B) void k_scan1(const int* __restrict__ deg,
                                                  int* __restrict__ off,
                                                  int* __restrict__ bsum) {
    __shared__ int s[SCAN_B];
    int t = threadIdx.x, g = blockIdx.x * SCAN_B + t;
    s[t] = (g < NN) ? deg[g] : 0;
    __syncthreads();
    for (int d = 1; d < SCAN_B; d <<= 1) {
        int add = (t >= d) ? s[t - d] : 0;
        __syncthreads();
        s[t] += add;
        __syncthreads();
    }
    if (g < NN) off[g + 1] = s[t];
    if (t == SCAN_B - 1) bsum[blockIdx.x] = s[t];
}
__global__ void k_scan2(int* __restrict__ bsum, int nb) {
    if (threadIdx.x == 0 && blockIdx.x == 0) {
        int acc = 0;
        for (int i = 0; i < nb; i++) { int v = bsum[i]; bsum[i] = acc; acc += v; }
    }
}
__global__ void k_scan3(int* __restrict__ off, const int* __restrict__ bsum) {
    int g = blockIdx.x * 256 + threadIdx.x;
    if (g == 0) off[0] = 0;
    if (g < NN) off[g + 1] += bsum[g / SCAN_B];
}
__global__ void k_cur(const int* __restrict__ off, int* __restrict__ cur) {
    int g = blockIdx.x * 256 + threadIdx.x;
    if (g < NN) cur[g] = off[g];
}
__global__ void k_fill(const int* __restrict__ src, const int* __restrict__ dst,
                       int* __restrict__ cur, int* __restrict__ csr) {
    int e = blockIdx.x * 256 + threadIdx.x;
    if (e < NE) {
        int p = atomicAdd(&cur[dst[e]], 1);
        csr[p] = src[e];
    }
}

// ---------------- propagation: CSR gather, no atomics ----------------
__global__ __launch_bounds__(256) void k_prop_gather(const float* __restrict__ h_in,
        float* __restrict__ h_out, const float* __restrict__ norm,
        const int* __restrict__ off, const int* __restrict__ csr) {
    int t = blockIdx.x * 256 + threadIdx.x;
    int v = t >> 5, lane = t & 31;
    float nv = norm[v];
    float4 a = ((const float4*)(h_in + (size_t)v * FD))[lane];
    float4 acc = make_float4(a.x * nv, a.y * nv, a.z * nv, a.w * nv);
    int j1 = off[v + 1];
    for (int j = off[v]; j < j1; j++) {
        int s = csr[j];
        float ns = norm[s];
        float4 b = ((const float4*)(h_in + (size_t)s * FD))[lane];
        acc.x += ns * b.x; acc.y += ns * b.y; acc.z += ns * b.z; acc.w += ns * b.w;
    }
    acc.x *= nv; acc.y *= nv; acc.z *= nv; acc.w *= nv;
    ((float4*)(h_out + (size_t)v * FD))[lane] = acc;
}

// ---------------- weight packing ----------------
__global__ void k_pack_w(const float* __restrict__ Wsg, const float* __restrict__ W1,
                         const float* __restrict__ W2, uint4* __restrict__ wp) {
    int t = blockIdx.x * 256 + threadIdx.x;
    int wsel = t >> 11, r = t & 2047;
    const float* W = wsel == 0 ? Wsg : (wsel == 1 ? W1 : W2);
    int frag = r >> 6, l = r & 63;
    int nt = frag >> 2, kb = frag & 3;
    int col = 16 * nt + (l & 15);
    int k0 = 32 * kb + 8 * (l >> 4);
    unsigned q[4];
#pragma unroll
    for (int j = 0; j < 4; j++) {
        unsigned lo = f2bf(W[(size_t)(k0 + 2 * j) * FD + col]);
        unsigned hi = f2bf(W[(size_t)(k0 + 2 * j + 1) * FD + col]);
        q[j] = lo | (hi << 16);
    }
    wp[t] = make_uint4(q[0], q[1], q[2], q[3]);
}

#define ZS 136

// ---------------- SGConv linear via MFMA ----------------
__global__ __launch_bounds__(128) void k_sgconv_mfma(const float* __restrict__ hin,
        const uint4* __restrict__ wp, const float* __restrict__ bsg,
        unsigned short* __restrict__ hout) {
    __shared__ unsigned short z[128 * ZS];
    __shared__ uint4 wl[2048];
    int tid = threadIdx.x;
    int row0 = blockIdx.x * 128;
    for (int i = tid; i < 2048; i += 128) wl[i] = wp[i];
#pragma unroll 4
    for (int it = 0; it < 32; it++) {
        int idx = it * 128 + tid;
        int r = idx >> 5, c4 = idx & 31;
        float4 v = make_float4(0, 0, 0, 0);
        if (row0 + r < NN) v = *(const float4*)(hin + (size_t)(row0 + r) * FD + c4 * 4);
        unsigned lo = f2bf(v.x) | ((unsigned)f2bf(v.y) << 16);
        unsigned hi = f2bf(v.z) | ((unsigned)f2bf(v.w) << 16);
        *(uint2*)&z[r * ZS + c4 * 4] = make_uint2(lo, hi);
    }
    __syncthreads();

    int l = tid & 63, w = tid >> 6;
    f32x4 acc[4][8];
#pragma unroll
    for (int mt = 0; mt < 4; mt++)
#pragma unroll
        for (int nt = 0; nt < 8; nt++) acc[mt][nt] = (f32x4){0, 0, 0, 0};

#pragma unroll
    for (int kb = 0; kb < 4; kb++) {
        bf16x8 af[4];
#pragma unroll
        for (int mt = 0; mt < 4; mt++)
            af[mt] = *(const bf16x8*)&z[(w * 64 + mt * 16 + (l & 15)) * ZS + kb * 32 + (l >> 4) * 8];
#pragma unroll
        for (int nt = 0; nt < 8; nt++) {
            bf16x8 wf = *(const bf16x8*)((const unsigned short*)wl + ((nt * 4 + kb) * 64 + l) * 8);
#pragma unroll
            for (int mt = 0; mt < 4; mt++)
                acc[mt][nt] = __builtin_amdgcn_mfma_f32_16x16x32_bf16(af[mt], wf, acc[mt][nt], 0, 0, 0);
        }
    }
    __syncthreads();
    float bv[8];
#pragma unroll
    for (int nt = 0; nt < 8; nt++) bv[nt] = bsg[16 * nt + (l & 15)];
#pragma unroll
    for (int mt = 0; mt < 4; mt++)
#pragma unroll
        for (int nt = 0; nt < 8; nt++)
#pragma unroll
            for (int r = 0; r < 4; r++)
                z[(w * 64 + mt * 16 + (l >> 4) * 4 + r) * ZS + 16 * nt + (l & 15)] =
                    f2bf(acc[mt][nt][r] + bv[nt]);
    __syncthreads();
#pragma unroll 4
    for (int it = 0; it < 16; it++) {
        int idx = it * 128 + tid;
        int r = idx >> 4, c = idx & 15;
        if (row0 + r < NN)
            *(uint4*)(hout + (size_t)(row0 + r) * FD + c * 8) = *(const uint4*)&z[r * ZS + c * 8];
    }
}

// ---------------- predict MLP via MFMA (pos+neg) ----------------
// 256 threads (4 waves), 128 edges/block; weights read directly from global
// (L1/L2-hot). LDS = z only (34.8 KB) -> 4 blocks/CU = 16 waves/CU.
__global__ __launch_bounds__(256, 4) void k_predict_mfma(const unsigned short* __restrict__ h,
        const int* __restrict__ srcA, const int* __restrict__ dstA,
        const int* __restrict__ srcB, const int* __restrict__ dstB,
        const uint4* __restrict__ w1p, const uint4* __restrict__ w2p,
        const float* __restrict__ b1, const float* __restrict__ b2,
        const float* __restrict__ W3, const float* __restrict__ b3,
        float* __restrict__ out) {
    __shared__ unsigned short z[128 * ZS];
    int tid = threadIdx.x;
    int b = blockIdx.x;
    int half = b >= 3125;
    int eb = (b - (half ? 3125 : 0)) * 128;
    const int* S = half ? srcB : srcA;
    const int* D = half ? dstB : dstA;

    // stage z = h[s]*h[d] (bf16); 4 threads x 64B-chunks per edge, 2 iters
#pragma unroll
    for (int it = 0; it < 2; it++) {
        int e = (tid >> 2) + 64 * it;
        int p = tid & 3;
        int s = S[eb + e], d = D[eb + e];
        const uint4* hs = (const uint4*)(h + (size_t)s * FD + p * 32);
        const uint4* hd = (const uint4*)(h + (size_t)d * FD + p * 32);
        unsigned short* zr = z + e * ZS + p * 32;
#pragma unroll
        for (int q = 0; q < 4; q++) {
            uint4 a = hs[q], c = hd[q];
            uint4 r;
            r.x = mulbf2(a.x, c.x);
            r.y = mulbf2(a.y, c.y);
            r.z = mulbf2(a.z, c.z);
            r.w = mulbf2(a.w, c.w);
            *(uint4*)(zr + q * 8) = r;
        }
    }
    __syncthreads();

    int l = tid & 63, w = tid >> 6;   // wave w owns rows w*32 .. w*32+31 (mt=0,1)
    f32x4 acc[2][8];
#pragma unroll
    for (int mt = 0; mt < 2; mt++)
#pragma unroll
        for (int nt = 0; nt < 8; nt++) acc[mt][nt] = (f32x4){0, 0, 0, 0};

    // ---- layer 1 (W1 fragments from global) ----
#pragma unroll
    for (int kb = 0; kb < 4; kb++) {
        bf16x8 af[2];
#pragma unroll
        for (int mt = 0; mt < 2; mt++)
            af[mt] = *(const bf16x8*)&z[(w * 32 + mt * 16 + (l & 15)) * ZS + kb * 32 + (l >> 4) * 8];
#pragma unroll
        for (int nt = 0; nt < 8; nt++) {
            bf16x8 wf = *(const bf16x8*)&w1p[(nt * 4 + kb) * 64 + l];
#pragma unroll
            for (int mt = 0; mt < 2; mt++)
                acc[mt][nt] = __builtin_amdgcn_mfma_f32_16x16x32_bf16(af[mt], wf, acc[mt][nt], 0, 0, 0);
        }
    }
    __syncthreads();          // all layer-1 z reads done
    // write relu(acc + b1) back to z (own rows only)
#pragma unroll
    for (int mt = 0; mt < 2; mt++)
#pragma unroll
        for (int nt = 0; nt < 8; nt++) {
            float bv = b1[16 * nt + (l & 15)];
#pragma unroll
            for (int r = 0; r < 4; r++)
                z[(w * 32 + mt * 16 + (l >> 4) * 4 + r) * ZS + 16 * nt + (l & 15)] =
                    f2bf(fmaxf(acc[mt][nt][r] + bv, 0.0f));
        }
    __syncthreads();

    // ---- layer 2 (W2 fragments from global) ----
#pragma unroll
    for (int mt = 0; mt < 2; mt++)
#pragma unroll
        for (int nt = 0; nt < 8; nt++) acc[mt][nt] = (f32x4){0, 0, 0, 0};
#pragma unroll
    for (int kb = 0; kb < 4; kb++) {
        bf16x8 af[2];
#pragma unroll
        for (int mt = 0; mt < 2; mt++)
            af[mt] = *(const bf16x8*)&z[(w * 32 + mt * 16 + (l & 15)) * ZS + kb * 32 + (l >> 4) * 8];
#pragma unroll
        for (int nt = 0; nt < 8; nt++) {
            bf16x8 wf = *(const bf16x8*)&w2p[(nt * 4 + kb) * 64 + l];
#pragma unroll
            for (int mt = 0; mt < 2; mt++)
                acc[mt][nt] = __builtin_amdgcn_mfma_f32_16x16x32_bf16(af[mt], wf, acc[mt][nt], 0, 0, 0);
        }
    }

    // ---- epilogue: relu(acc + b2) . W3 + b3 ----
    {
        float bb3 = b3[0];
#pragma unroll
        for (int mt = 0; mt < 2; mt++)
#pragma unroll
            for (int r = 0; r < 4; r++) {
                float p = 0.0f;
#pragma unroll
                for (int nt = 0; nt < 8; nt++)
                    p += fmaxf(acc[mt][nt][r] + b2[16 * nt + (l & 15)], 0.0f) * W3[16 * nt + (l & 15)];
                p += __shfl_xor(p, 1);
                p += __shfl_xor(p, 2);
                p += __shfl_xor(p, 4);
                p += __shfl_xor(p, 8);
                if ((l & 15) == 0)
                    out[(size_t)half * NE + eb + w * 32 + mt * 16 + (l >> 4) * 4 + r] = p + bb3;
            }
    }
}

// ---------------- launch ----------------
extern "C" void kernel_launch(void* const* d_in, const int* in_sizes, int n_in,
                              void* d_out, int out_size, void* d_ws, size_t ws_size,
                              hipStream_t stream) {
    const float* x    = (const float*)d_in[0];
    const int* src    = (const int*)d_in[1];
    const int* dst    = (const int*)d_in[2];
    const int* nsrc   = (const int*)d_in[3];
    const int* ndst   = (const int*)d_in[4];
    const float* W_sg = (const float*)d_in[5];
    const float* b_sg = (const float*)d_in[6];
    const float* W1   = (const float*)d_in[7];
    const float* b1   = (const float*)d_in[8];
    const float* W2   = (const float*)d_in[9];
    const float* b2   = (const float*)d_in[10];
    const float* W3   = (const float*)d_in[11];
    const float* b3   = (const float*)d_in[12];
    float* out = (float*)d_out;

    char* p = (char*)d_ws;
    float* norm = (float*)p;  p += 400000;               // NN f32
    int*   deg  = (int*)p;    p += 400000;               // NN i32
    int*   off  = (int*)p;    p += 400016;               // NN+1 i32
    int*   cur  = (int*)p;    p += 400000;               // NN i32
    int*   bsum = (int*)p;    p += 512;                  // 98 i32
    int*   csr  = (int*)p;    p += 1600000;              // NE i32
    uint4* wp   = (uint4*)p;  p += 98304;                // 3 x 2048 uint4
    float* bufA = (float*)p;  p += (size_t)NN * FD * 4;  // 51.2 MB
    float* bufB = (float*)p;                             // 51.2 MB
    unsigned short* hbf = (unsigned short*)bufB;

    const int gN = (NN + 255) / 256;
    const int gE = (NE + 255) / 256;
    const int nb = (NN + SCAN_B - 1) / SCAN_B;

    k_pack_w<<<24, 256, 0, stream>>>(W_sg, W1, W2, wp);

    // CSR build
    k_deg_init<<<gN, 256, 0, stream>>>(deg);
    k_deg_count<<<gE, 256, 0, stream>>>(dst, deg);
    k_norm<<<gN, 256, 0, stream>>>(deg, norm);
    k_scan1<<<nb, SCAN_B, 0, stream>>>(deg, off, bsum);
    k_scan2<<<1, 64, 0, stream>>>(bsum, nb);
    k_scan3<<<gN, 256, 0, stream>>>(off, bsum);
    k_cur<<<gN, 256, 0, stream>>>(off, cur);
    k_fill<<<gE, 256, 0, stream>>>(src, dst, cur, csr);

    // propagation: x -> bufA -> bufB -> bufA (norm folded in)
    k_prop_gather<<<NN * 32 / 256, 256, 0, stream>>>(x, bufA, norm, off, csr);
    k_prop_gather<<<NN * 32 / 256, 256, 0, stream>>>(bufA, bufB, norm, off, csr);
    k_prop_gather<<<NN * 32 / 256, 256, 0, stream>>>(bufB, bufA, norm, off, csr);

    // SGConv linear (MFMA) -> bf16 h (into bufB)
    k_sgconv_mfma<<<(NN + 127) / 128, 128, 0, stream>>>(bufA, wp, b_sg, hbf);

    // predict MLP (MFMA), pos + neg
    k_predict_mfma<<<6250, 256, 0, stream>>>(hbf, src, dst, nsrc, ndst,
                                             wp + 2048, wp + 4096,
                                             b1, b2, W3, b3, out);
}